// Round 6
// baseline (1383.905 us; speedup 1.0000x reference)
//
#include <hip/hip_runtime.h>
#include <hip/hip_bf16.h>

typedef __bf16 bf16;
typedef __attribute__((ext_vector_type(4))) __bf16 bf16x4;
typedef __attribute__((ext_vector_type(8))) __bf16 bf16x8;
typedef __attribute__((ext_vector_type(4))) float f32x4;

// ---------------- async global->LDS helper (16B per lane, wave-uniform LDS base) ----
__device__ __forceinline__ void async_ld16(const void* g, void* l) {
    __builtin_amdgcn_global_load_lds(
        (const __attribute__((address_space(1))) unsigned int*)g,
        (__attribute__((address_space(3))) unsigned int*)l, 16, 0, 0);
}

// ---------------- fp32 -> bf16 transposed weight convert: in[K][N] -> out[N][K] ----
__global__ __launch_bounds__(256) void k_f2bt(const float* __restrict__ in,
                                              bf16* __restrict__ out, int Kd, int Nd) {
    int id = blockIdx.x * 256 + threadIdx.x;
    if (id >= Kd * Nd) return;
    int k = id / Nd, n = id - k * Nd;
    out[(size_t)n * Kd + k] = (bf16)in[id];
}

// ---------------- fused reorder_in + LayerNorm1(l=0) -------------------------------
// reads x in raw (B,H,W,C) order; writes xres (fp32 copy) and h (LN'd bf16) at the
// windowed token position. one wave per token.
__global__ __launch_bounds__(256) void k_lnr(const float* __restrict__ x,
                                             const float* __restrict__ s,
                                             const float* __restrict__ b,
                                             float* __restrict__ xres,
                                             bf16* __restrict__ h) {
    int traw = blockIdx.x * 4 + (threadIdx.x >> 6);
    int lane = threadIdx.x & 63;
    int bb = traw / 3136;
    int rem = traw - bb * 3136;
    int y = rem / 56, xc = rem - y * 56;
    int w = bb * 64 + (y / 7) * 8 + (xc / 7);
    int n = (y % 7) * 7 + (xc % 7);
    int twin = w * 49 + n;

    const float4* row = (const float4*)(x + (size_t)traw * 384);  // 96 float4
    float4 v0 = row[lane];
    float4 v1 = make_float4(0.f, 0.f, 0.f, 0.f);
    if (lane < 32) v1 = row[64 + lane];
    float sum = v0.x + v0.y + v0.z + v0.w + v1.x + v1.y + v1.z + v1.w;
#pragma unroll
    for (int m = 1; m < 64; m <<= 1) sum += __shfl_xor(sum, m);
    float mu = sum * (1.f / 384.f);
    float sq = (v0.x - mu) * (v0.x - mu) + (v0.y - mu) * (v0.y - mu) +
               (v0.z - mu) * (v0.z - mu) + (v0.w - mu) * (v0.w - mu);
    if (lane < 32)
        sq += (v1.x - mu) * (v1.x - mu) + (v1.y - mu) * (v1.y - mu) +
              (v1.z - mu) * (v1.z - mu) + (v1.w - mu) * (v1.w - mu);
#pragma unroll
    for (int m = 1; m < 64; m <<= 1) sq += __shfl_xor(sq, m);
    float r = rsqrtf(sq * (1.f / 384.f) + 1e-6f);

    float4* xr = (float4*)(xres + (size_t)twin * 384);
    const float4* s4 = (const float4*)s;
    const float4* b4 = (const float4*)b;
    bf16* ho = h + (size_t)twin * 384;
    {
        xr[lane] = v0;
        float4 sv = s4[lane], bv = b4[lane];
        bf16x4 ov;
        ov[0] = (bf16)((v0.x - mu) * r * sv.x + bv.x);
        ov[1] = (bf16)((v0.y - mu) * r * sv.y + bv.y);
        ov[2] = (bf16)((v0.z - mu) * r * sv.z + bv.z);
        ov[3] = (bf16)((v0.w - mu) * r * sv.w + bv.w);
        *(bf16x4*)&ho[lane * 4] = ov;
    }
    if (lane < 32) {
        xr[64 + lane] = v1;
        float4 sv = s4[64 + lane], bv = b4[64 + lane];
        bf16x4 ov;
        ov[0] = (bf16)((v1.x - mu) * r * sv.x + bv.x);
        ov[1] = (bf16)((v1.y - mu) * r * sv.y + bv.y);
        ov[2] = (bf16)((v1.z - mu) * r * sv.z + bv.z);
        ov[3] = (bf16)((v1.w - mu) * r * sv.w + bv.w);
        *(bf16x4*)&ho[256 + lane * 4] = ov;
    }
}

// ---------------- GELU (tanh approximation, matches jax.nn.gelu) -------------------
__device__ inline float gelu_f(float x) {
    float u = 0.7978845608028654f * (x + 0.044715f * x * x * x);
    float t = 1.f - 2.f / (__expf(2.f * u) + 1.f);
    return 0.5f * x * (1.f + t);
}

// ---------------- GEMM (wide-N): C[M,N] = A[M,K] @ Bt[N,K]^T, N in {1152,1536} -----
// EPI 0: store bf16 | 1: +bias, gelu, store bf16
// 128x128 tile, BK=32, 4 waves (2x2), global_load_lds staging, XOR kseg swizzle.
template <int EPI>
__global__ __launch_bounds__(256) void k_gemm(const bf16* __restrict__ A,
                                              const bf16* __restrict__ Bt,
                                              const float* __restrict__ bias,
                                              bf16* __restrict__ Cout,
                                              int N, int K) {
    __shared__ __align__(16) char lds[17408];
    bf16* As = (bf16*)lds;                 // 128x32 bf16 = 8192 B, swizzled ksegs
    bf16* Bs = (bf16*)(lds + 8192);        // 128x32 bf16 = 8192 B
    int tid = threadIdx.x;
    int n0 = blockIdx.x * 128;
    int m0 = blockIdx.y * 128;
    int wave = tid >> 6, lane = tid & 63;
    int wm = (wave >> 1) * 64, wn = (wave & 1) * 64;
    int col = lane & 15, quad = lane >> 4;

    f32x4 acc[4][4] = {};

    int r0 = 2 * wave * 16 + (lane >> 2);
    int ksl = (lane & 3) ^ ((r0 >> 1) & 3);
    const bf16* ga0 = A + (size_t)(m0 + r0) * K + ksl * 8;
    const bf16* gb0 = Bt + (size_t)(n0 + r0) * K + ksl * 8;
    size_t rowK16 = (size_t)16 * K;
    bf16* la0 = &As[2 * wave * 512];
    bf16* la1 = &As[(2 * wave + 1) * 512];
    bf16* lb0 = &Bs[2 * wave * 512];
    bf16* lb1 = &Bs[(2 * wave + 1) * 512];

    for (int kb = 0; kb < K; kb += 32) {
        __syncthreads();
        async_ld16(ga0 + kb, la0);
        async_ld16(ga0 + rowK16 + kb, la1);
        async_ld16(gb0 + kb, lb0);
        async_ld16(gb0 + rowK16 + kb, lb1);
        __syncthreads();

        bf16x8 af[4], bfv[4];
#pragma unroll
        for (int i = 0; i < 4; i++) {
            int ra = wm + i * 16 + col;
            af[i] = *(const bf16x8*)&As[ra * 32 + ((quad ^ ((ra >> 1) & 3)) << 3)];
            int rb = wn + i * 16 + col;
            bfv[i] = *(const bf16x8*)&Bs[rb * 32 + ((quad ^ ((rb >> 1) & 3)) << 3)];
        }
#pragma unroll
        for (int mi = 0; mi < 4; mi++)
#pragma unroll
            for (int ni = 0; ni < 4; ni++)
                acc[mi][ni] = __builtin_amdgcn_mfma_f32_16x16x32_bf16(
                    af[mi], bfv[ni], acc[mi][ni], 0, 0, 0);
    }

    __syncthreads();   // LDS becomes epilogue scratch
    float* scrw = (float*)lds + wave * (16 * 68);

    int prow = lane >> 3;
    int pc0 = (lane & 7) * 8;
#pragma unroll
    for (int mi = 0; mi < 4; mi++) {
#pragma unroll
        for (int ni = 0; ni < 4; ni++)
#pragma unroll
            for (int r = 0; r < 4; r++)
                scrw[(quad * 4 + r) * 68 + ni * 16 + col] = acc[mi][ni][r];
#pragma unroll
        for (int h = 0; h < 2; h++) {
            int lr = h * 8 + prow;
            const float* sp = scrw + lr * 68 + pc0;
            float4 u0 = *(const float4*)sp;
            float4 u1 = *(const float4*)(sp + 4);
            int gm = m0 + wm + mi * 16 + lr;
            int gn = n0 + wn + pc0;
            size_t off = (size_t)gm * N + gn;
            if (EPI == 0) {
                bf16x8 ov;
                ov[0] = (bf16)u0.x; ov[1] = (bf16)u0.y; ov[2] = (bf16)u0.z; ov[3] = (bf16)u0.w;
                ov[4] = (bf16)u1.x; ov[5] = (bf16)u1.y; ov[6] = (bf16)u1.z; ov[7] = (bf16)u1.w;
                *(bf16x8*)&Cout[off] = ov;
            } else {
                float4 b0 = *(const float4*)&bias[gn];
                float4 b1 = *(const float4*)&bias[gn + 4];
                bf16x8 ov;
                ov[0] = (bf16)gelu_f(u0.x + b0.x); ov[1] = (bf16)gelu_f(u0.y + b0.y);
                ov[2] = (bf16)gelu_f(u0.z + b0.z); ov[3] = (bf16)gelu_f(u0.w + b0.w);
                ov[4] = (bf16)gelu_f(u1.x + b1.x); ov[5] = (bf16)gelu_f(u1.y + b1.y);
                ov[6] = (bf16)gelu_f(u1.z + b1.z); ov[7] = (bf16)gelu_f(u1.w + b1.w);
                *(bf16x8*)&Cout[off] = ov;
            }
        }
    }
}

// ---------------- fused GEMM (N=384) + residual + LayerNorm ------------------------
// MODE 0: resid += val;           LN -> hout          (proj + ln2)
// MODE 1: resid += val + bias;    LN -> hout          (mlp2 + ln1 of next layer)
// MODE 2: out[perm] = val + bias + resid  (fp32)      (final mlp2 + reorder_out)
// Block: 64 rows x 384 cols, 4 waves (each 64x96, 4x6 accs). Grid: M/64 = 784.
template <int MODE>
__global__ __launch_bounds__(256) void k_gemm_ln(const bf16* __restrict__ A,
                                                 const bf16* __restrict__ Bt,
                                                 const float* __restrict__ bias,
                                                 float* __restrict__ resid,
                                                 const float* __restrict__ lns,
                                                 const float* __restrict__ lnb,
                                                 bf16* __restrict__ hout,
                                                 float* __restrict__ outp,
                                                 int K) {
    __shared__ __align__(16) bf16 As[64 * 32];    // 4 KB
    __shared__ __align__(16) bf16 Bs[384 * 32];   // 24 KB
    __shared__ float pstat[64][4][2];
    __shared__ float sS[384], bS[384], biasS[384];
    int tid = threadIdx.x;
    int wave = tid >> 6, lane = tid & 63;
    int col = lane & 15, quad = lane >> 4;
    int m0 = blockIdx.x * 64;
    int j0 = wave * 96;

    for (int t = tid; t < 384; t += 256) {
        if (MODE != 2) { sS[t] = lns[t]; bS[t] = lnb[t]; }
        if (MODE != 0) biasS[t] = bias[t];
    }

    f32x4 acc[4][6] = {};

    // A staging: wave stages rows [16w, 16w+16)
    int arow = 16 * wave + (lane >> 2);
    int aks = ((lane & 3) ^ ((arow >> 1) & 3)) << 3;
    const bf16* ga = A + (size_t)(m0 + arow) * K + aks;
    bf16* la = &As[wave * 512];
    // B staging: wave stages chunks {w, w+4, ..., w+20}
    const bf16* gb[6];
    bf16* lb[6];
#pragma unroll
    for (int c = 0; c < 6; c++) {
        int brow = 16 * (wave + 4 * c) + (lane >> 2);
        int bks = ((lane & 3) ^ ((brow >> 1) & 3)) << 3;
        gb[c] = Bt + (size_t)brow * K + bks;
        lb[c] = &Bs[(wave + 4 * c) * 512];
    }

    for (int kb = 0; kb < K; kb += 32) {
        __syncthreads();
        async_ld16(ga + kb, la);
#pragma unroll
        for (int c = 0; c < 6; c++) async_ld16(gb[c] + kb, lb[c]);
        __syncthreads();

        bf16x8 af[4], bfv[6];
#pragma unroll
        for (int i = 0; i < 4; i++) {
            int ra = i * 16 + col;
            af[i] = *(const bf16x8*)&As[ra * 32 + ((quad ^ ((ra >> 1) & 3)) << 3)];
        }
#pragma unroll
        for (int i = 0; i < 6; i++) {
            int rb = j0 + i * 16 + col;
            bfv[i] = *(const bf16x8*)&Bs[rb * 32 + ((quad ^ ((rb >> 1) & 3)) << 3)];
        }
#pragma unroll
        for (int mi = 0; mi < 4; mi++)
#pragma unroll
            for (int ni = 0; ni < 6; ni++)
                acc[mi][ni] = __builtin_amdgcn_mfma_f32_16x16x32_bf16(
                    af[mi], bfv[ni], acc[mi][ni], 0, 0, 0);
    }

    // epilogue pass 1: bias + residual add, partial LN stats (or permuted out store)
#pragma unroll
    for (int mi = 0; mi < 4; mi++) {
        float psum[4] = {0.f, 0.f, 0.f, 0.f};
        float psq[4] = {0.f, 0.f, 0.f, 0.f};
#pragma unroll
        for (int ni = 0; ni < 6; ni++) {
            int j = j0 + ni * 16 + col;
            float bv = (MODE == 0) ? 0.f : biasS[j];
            size_t off = (size_t)(m0 + mi * 16 + quad * 4) * 384 + j;
#pragma unroll
            for (int r = 0; r < 4; r++) {
                float v = acc[mi][ni][r] + bv + resid[off + (size_t)r * 384];
                acc[mi][ni][r] = v;
                if (MODE != 2) {
                    resid[off + (size_t)r * 384] = v;
                    psum[r] += v;
                    psq[r] += v * v;
                }
            }
        }
        if (MODE != 2) {
#pragma unroll
            for (int r = 0; r < 4; r++) {
#pragma unroll
                for (int m = 1; m < 16; m <<= 1) {
                    psum[r] += __shfl_xor(psum[r], m);
                    psq[r] += __shfl_xor(psq[r], m);
                }
                if (col == 0) {
                    int il = mi * 16 + quad * 4 + r;
                    pstat[il][wave][0] = psum[r];
                    pstat[il][wave][1] = psq[r];
                }
            }
        } else {
#pragma unroll
            for (int r = 0; r < 4; r++) {
                int gm = m0 + mi * 16 + quad * 4 + r;
                int w = gm / 49, n = gm - w * 49;
                int bb = w >> 6, r64 = w & 63;
                int yy = (r64 >> 3) * 7 + n / 7;
                int xx = (r64 & 7) * 7 + n % 7;
                size_t traw = ((size_t)((bb * 56 + yy) * 56 + xx)) * 384;
#pragma unroll
                for (int ni = 0; ni < 6; ni++)
                    outp[traw + j0 + ni * 16 + col] = acc[mi][ni][r];
            }
        }
    }

    if (MODE != 2) {
        __syncthreads();
#pragma unroll
        for (int mi = 0; mi < 4; mi++) {
#pragma unroll
            for (int r = 0; r < 4; r++) {
                int il = mi * 16 + quad * 4 + r;
                float s = pstat[il][0][0] + pstat[il][1][0] + pstat[il][2][0] + pstat[il][3][0];
                float sq = pstat[il][0][1] + pstat[il][1][1] + pstat[il][2][1] + pstat[il][3][1];
                float mu = s * (1.f / 384.f);
                float var = fmaxf(sq * (1.f / 384.f) - mu * mu, 0.f);
                float rstd = rsqrtf(var + 1e-6f);
                size_t ho = (size_t)(m0 + il) * 384;
#pragma unroll
                for (int ni = 0; ni < 6; ni++) {
                    int j = j0 + ni * 16 + col;
                    hout[ho + j] = (bf16)((acc[mi][ni][r] - mu) * rstd * sS[j] + bS[j]);
                }
            }
        }
    }
}

// ---------------- MFMA window attention: one WAVE per (window, head) ---------------
__global__ __launch_bounds__(256) void k_attn(const bf16* __restrict__ qkv,
                                              const float* __restrict__ rpb,
                                              bf16* __restrict__ o) {
    __shared__ unsigned short relIdx[2401];
    __shared__ float rpbs[4][169];
    __shared__ __align__(16) bf16 Vs[4][32 * 72];
    __shared__ __align__(16) bf16 Ps[4][64 * 72];

    int tid = threadIdx.x;
    int wave = tid >> 6, lane = tid & 63;
    int col = lane & 15, quad = lane >> 4;
    int w = blockIdx.x;
    int head = blockIdx.y * 4 + wave;
    const float scale = 0.17677669529663687f;

    for (int e = tid; e < 2401; e += 256) {
        int i = e / 49, j = e - i * 49;
        int yi = i / 7, xi = i - yi * 7, yj = j / 7, xj = j - yj * 7;
        relIdx[e] = (unsigned short)((yi - yj + 6) * 13 + (xi - xj + 6));
    }
    for (int e = lane; e < 169; e += 64) rpbs[wave][e] = rpb[e * 12 + head];

    const bf16* base = qkv + (size_t)w * 49 * 1152 + head * 32;
    bf16* vsw = Vs[wave];
    bf16* psw = Ps[wave];

    bf16x4 z4 = {(bf16)0.f, (bf16)0.f, (bf16)0.f, (bf16)0.f};
    for (int e = lane; e < 576; e += 64) *(bf16x4*)&vsw[e * 4] = z4;
    for (int e = lane; e < 392; e += 64) {
        int j = e >> 3, d4 = (e & 7) * 4;
        bf16x4 vv = *(const bf16x4*)&base[768 + (size_t)j * 1152 + d4];
        vsw[(d4 + 0) * 72 + j] = vv[0];
        vsw[(d4 + 1) * 72 + j] = vv[1];
        vsw[(d4 + 2) * 72 + j] = vv[2];
        vsw[(d4 + 3) * 72 + j] = vv[3];
    }

    __syncthreads();

    bf16x8 qf[4], kf[4];
#pragma unroll
    for (int mi = 0; mi < 4; mi++) {
        size_t row = (size_t)(mi * 16 + col) * 1152 + quad * 8;
        qf[mi] = *(const bf16x8*)&base[row];
        kf[mi] = *(const bf16x8*)&base[384 + row];
    }

    f32x4 S[4][4] = {};
#pragma unroll
    for (int mi = 0; mi < 4; mi++)
#pragma unroll
        for (int nj = 0; nj < 4; nj++)
            S[mi][nj] = __builtin_amdgcn_mfma_f32_16x16x32_bf16(qf[mi], kf[nj], S[mi][nj], 0, 0, 0);

    float* rp = rpbs[wave];
#pragma unroll
    for (int mi = 0; mi < 4; mi++) {
#pragma unroll
        for (int r = 0; r < 4; r++) {
            int ii = mi * 16 + quad * 4 + r;
            int ir = (ii < 49 ? ii : 0) * 49;
            float sv[4];
            float mx = -1e30f;
#pragma unroll
            for (int nj = 0; nj < 4; nj++) {
                int j = nj * 16 + col;
                float v;
                if (j < 49) v = S[mi][nj][r] * scale + rp[relIdx[ir + j]];
                else v = -1e30f;
                sv[nj] = v;
                mx = fmaxf(mx, v);
            }
#pragma unroll
            for (int m = 1; m < 16; m <<= 1) mx = fmaxf(mx, __shfl_xor(mx, m));
            float sum = 0.f;
#pragma unroll
            for (int nj = 0; nj < 4; nj++) {
                float p = __expf(sv[nj] - mx);
                sv[nj] = p;
                sum += p;
            }
#pragma unroll
            for (int m = 1; m < 16; m <<= 1) sum += __shfl_xor(sum, m);
            float is = 1.f / sum;
#pragma unroll
            for (int nj = 0; nj < 4; nj++)
                psw[ii * 72 + nj * 16 + col] = (bf16)(sv[nj] * is);
        }
    }

    __syncthreads();

    f32x4 O[4][2] = {};
#pragma unroll
    for (int kt = 0; kt < 2; kt++) {
        bf16x8 vb[2];
#pragma unroll
        for (int nt = 0; nt < 2; nt++)
            vb[nt] = *(const bf16x8*)&vsw[(nt * 16 + col) * 72 + kt * 32 + quad * 8];
#pragma unroll
        for (int mi = 0; mi < 4; mi++) {
            bf16x8 pa = *(const bf16x8*)&psw[(mi * 16 + col) * 72 + kt * 32 + quad * 8];
#pragma unroll
            for (int nt = 0; nt < 2; nt++)
                O[mi][nt] = __builtin_amdgcn_mfma_f32_16x16x32_bf16(pa, vb[nt], O[mi][nt], 0, 0, 0);
        }
    }

    bf16* ob = o + (size_t)w * 49 * 384 + head * 32;
#pragma unroll
    for (int mi = 0; mi < 4; mi++) {
#pragma unroll
        for (int r = 0; r < 4; r++) {
            int i = mi * 16 + quad * 4 + r;
            if (i < 49) {
#pragma unroll
                for (int nt = 0; nt < 2; nt++)
                    ob[(size_t)i * 384 + nt * 16 + col] = (bf16)O[mi][nt][r];
            }
        }
    }
}

// ---------------- launch ----------------
extern "C" void kernel_launch(void* const* d_in, const int* in_sizes, int n_in,
                              void* d_out, int out_size, void* d_ws, size_t ws_size,
                              hipStream_t stream) {
    const float* x      = (const float*)d_in[0];
    const float* ln1_s  = (const float*)d_in[1];
    const float* ln1_b  = (const float*)d_in[2];
    const float* qkv_w  = (const float*)d_in[3];
    const float* rpb    = (const float*)d_in[4];
    const float* proj_w = (const float*)d_in[5];
    const float* ln2_s  = (const float*)d_in[6];
    const float* ln2_b  = (const float*)d_in[7];
    const float* mlp_w1 = (const float*)d_in[8];
    const float* mlp_b1 = (const float*)d_in[9];
    const float* mlp_w2 = (const float*)d_in[10];
    const float* mlp_b2 = (const float*)d_in[11];
    float* out = (float*)d_out;

    char* ws = (char*)d_ws;
    float* xres  = (float*)ws;                     // 77,070,336 B
    bf16* qkvbuf = (bf16*)(ws + 77070336);         // 115,605,504 B
    bf16* obuf   = (bf16*)(ws + 192675840);        // 38,535,168 B
    bf16* wbuf   = (bf16*)(ws + 231211008);        // 7,077,888 B
    bf16* hidden = qkvbuf;                         // aliases qkv+obuf (154,140,672 B)
    bf16* hbuf   = (bf16*)d_out;                   // 38.5 MB scratch inside 77 MB out

    bf16* qkvw_b  = wbuf;                 // 884,736 elems (2 layers, transposed [N][K])
    bf16* projw_b = wbuf + 884736;        // 294,912
    bf16* mlp1_b  = wbuf + 1179648;       // 1,179,648
    bf16* mlp2_b  = wbuf + 2359296;       // 1,179,648

    for (int l = 0; l < 2; l++) {
        k_f2bt<<<1728, 256, 0, stream>>>(qkv_w + (size_t)l * 442368,
                                         qkvw_b + (size_t)l * 442368, 384, 1152);
        k_f2bt<<<576, 256, 0, stream>>>(proj_w + (size_t)l * 147456,
                                        projw_b + (size_t)l * 147456, 384, 384);
        k_f2bt<<<2304, 256, 0, stream>>>(mlp_w1 + (size_t)l * 589824,
                                         mlp1_b + (size_t)l * 589824, 384, 1536);
        k_f2bt<<<2304, 256, 0, stream>>>(mlp_w2 + (size_t)l * 589824,
                                         mlp2_b + (size_t)l * 589824, 1536, 384);
    }

    // fused reorder_in + LN1(l=0)
    k_lnr<<<12544, 256, 0, stream>>>(x, ln1_s, ln1_b, xres, hbuf);

    for (int l = 0; l < 2; l++) {
        k_gemm<0><<<dim3(9, 392), 256, 0, stream>>>(
            hbuf, qkvw_b + (size_t)l * 442368, nullptr, qkvbuf, 1152, 384);
        k_attn<<<dim3(1024, 3), 256, 0, stream>>>(qkvbuf, rpb + l * 2028, obuf);
        k_gemm_ln<0><<<784, 256, 0, stream>>>(
            obuf, projw_b + (size_t)l * 147456, nullptr, xres,
            ln2_s + l * 384, ln2_b + l * 384, hbuf, nullptr, 384);
        k_gemm<1><<<dim3(12, 392), 256, 0, stream>>>(
            hbuf, mlp1_b + (size_t)l * 589824, mlp_b1 + l * 1536, hidden, 1536, 384);
        if (l == 0) {
            k_gemm_ln<1><<<784, 256, 0, stream>>>(
                hidden, mlp2_b, mlp_b2, xres,
                ln1_s + 384, ln1_b + 384, hbuf, nullptr, 1536);
        } else {
            k_gemm_ln<2><<<784, 256, 0, stream>>>(
                hidden, mlp2_b + 589824, mlp_b2 + 384, xres,
                nullptr, nullptr, nullptr, out, 1536);
        }
    }
}

// Round 7
// 1226.957 us; speedup vs baseline: 1.1279x; 1.1279x over previous
//
#include <hip/hip_runtime.h>
#include <hip/hip_bf16.h>

typedef __bf16 bf16;
typedef __attribute__((ext_vector_type(4))) __bf16 bf16x4;
typedef __attribute__((ext_vector_type(8))) __bf16 bf16x8;
typedef __attribute__((ext_vector_type(4))) float f32x4;

// ---------------- async global->LDS helper (16B per lane, wave-uniform LDS base) ----
__device__ __forceinline__ void async_ld16(const void* g, void* l) {
    __builtin_amdgcn_global_load_lds(
        (const __attribute__((address_space(1))) unsigned int*)g,
        (__attribute__((address_space(3))) unsigned int*)l, 16, 0, 0);
}

// ---------------- fp32 -> bf16 transposed weight convert: in[K][N] -> out[N][K] ----
__global__ __launch_bounds__(256) void k_f2bt(const float* __restrict__ in,
                                              bf16* __restrict__ out, int Kd, int Nd) {
    int id = blockIdx.x * 256 + threadIdx.x;
    if (id >= Kd * Nd) return;
    int k = id / Nd, n = id - k * Nd;
    out[(size_t)n * Kd + k] = (bf16)in[id];
}

// ---------------- fused reorder_in + LayerNorm1(l=0): one wave per token -----------
__global__ __launch_bounds__(256) void k_lnr(const float* __restrict__ x,
                                             const float* __restrict__ s,
                                             const float* __restrict__ b,
                                             float* __restrict__ xres,
                                             bf16* __restrict__ h) {
    int traw = blockIdx.x * 4 + (threadIdx.x >> 6);
    int lane = threadIdx.x & 63;
    int bb = traw / 3136;
    int rem = traw - bb * 3136;
    int y = rem / 56, xc = rem - y * 56;
    int w = bb * 64 + (y / 7) * 8 + (xc / 7);
    int n = (y % 7) * 7 + (xc % 7);
    int twin = w * 49 + n;

    const float4* row = (const float4*)(x + (size_t)traw * 384);  // 96 float4
    float4 v0 = row[lane];
    float4 v1 = make_float4(0.f, 0.f, 0.f, 0.f);
    if (lane < 32) v1 = row[64 + lane];
    float sum = v0.x + v0.y + v0.z + v0.w + v1.x + v1.y + v1.z + v1.w;
#pragma unroll
    for (int m = 1; m < 64; m <<= 1) sum += __shfl_xor(sum, m);
    float mu = sum * (1.f / 384.f);
    float sq = (v0.x - mu) * (v0.x - mu) + (v0.y - mu) * (v0.y - mu) +
               (v0.z - mu) * (v0.z - mu) + (v0.w - mu) * (v0.w - mu);
    if (lane < 32)
        sq += (v1.x - mu) * (v1.x - mu) + (v1.y - mu) * (v1.y - mu) +
              (v1.z - mu) * (v1.z - mu) + (v1.w - mu) * (v1.w - mu);
#pragma unroll
    for (int m = 1; m < 64; m <<= 1) sq += __shfl_xor(sq, m);
    float r = rsqrtf(sq * (1.f / 384.f) + 1e-6f);

    float4* xr = (float4*)(xres + (size_t)twin * 384);
    const float4* s4 = (const float4*)s;
    const float4* b4 = (const float4*)b;
    bf16* ho = h + (size_t)twin * 384;
    {
        xr[lane] = v0;
        float4 sv = s4[lane], bv = b4[lane];
        bf16x4 ov;
        ov[0] = (bf16)((v0.x - mu) * r * sv.x + bv.x);
        ov[1] = (bf16)((v0.y - mu) * r * sv.y + bv.y);
        ov[2] = (bf16)((v0.z - mu) * r * sv.z + bv.z);
        ov[3] = (bf16)((v0.w - mu) * r * sv.w + bv.w);
        *(bf16x4*)&ho[lane * 4] = ov;
    }
    if (lane < 32) {
        xr[64 + lane] = v1;
        float4 sv = s4[64 + lane], bv = b4[64 + lane];
        bf16x4 ov;
        ov[0] = (bf16)((v1.x - mu) * r * sv.x + bv.x);
        ov[1] = (bf16)((v1.y - mu) * r * sv.y + bv.y);
        ov[2] = (bf16)((v1.z - mu) * r * sv.z + bv.z);
        ov[3] = (bf16)((v1.w - mu) * r * sv.w + bv.w);
        *(bf16x4*)&ho[256 + lane * 4] = ov;
    }
}

// ---------------- LayerNorm: fp32 residual -> bf16 ---------------------------------
__global__ __launch_bounds__(256) void k_ln(const float* __restrict__ xres,
                                            const float* __restrict__ s,
                                            const float* __restrict__ b,
                                            bf16* __restrict__ h) {
    int t = blockIdx.x * 4 + (threadIdx.x >> 6);
    int lane = threadIdx.x & 63;
    const float4* row = (const float4*)(xres + (size_t)t * 384);
    float4 v0 = row[lane];
    float4 v1 = make_float4(0.f, 0.f, 0.f, 0.f);
    if (lane < 32) v1 = row[64 + lane];
    float sum = v0.x + v0.y + v0.z + v0.w + v1.x + v1.y + v1.z + v1.w;
#pragma unroll
    for (int m = 1; m < 64; m <<= 1) sum += __shfl_xor(sum, m);
    float mu = sum * (1.f / 384.f);
    float sq = (v0.x - mu) * (v0.x - mu) + (v0.y - mu) * (v0.y - mu) +
               (v0.z - mu) * (v0.z - mu) + (v0.w - mu) * (v0.w - mu);
    if (lane < 32)
        sq += (v1.x - mu) * (v1.x - mu) + (v1.y - mu) * (v1.y - mu) +
              (v1.z - mu) * (v1.z - mu) + (v1.w - mu) * (v1.w - mu);
#pragma unroll
    for (int m = 1; m < 64; m <<= 1) sq += __shfl_xor(sq, m);
    float r = rsqrtf(sq * (1.f / 384.f) + 1e-6f);
    const float4* s4 = (const float4*)s;
    const float4* b4 = (const float4*)b;
    bf16* ho = h + (size_t)t * 384;
    {
        float4 sv = s4[lane], bv = b4[lane];
        bf16x4 ov;
        ov[0] = (bf16)((v0.x - mu) * r * sv.x + bv.x);
        ov[1] = (bf16)((v0.y - mu) * r * sv.y + bv.y);
        ov[2] = (bf16)((v0.z - mu) * r * sv.z + bv.z);
        ov[3] = (bf16)((v0.w - mu) * r * sv.w + bv.w);
        *(bf16x4*)&ho[lane * 4] = ov;
    }
    if (lane < 32) {
        float4 sv = s4[64 + lane], bv = b4[64 + lane];
        bf16x4 ov;
        ov[0] = (bf16)((v1.x - mu) * r * sv.x + bv.x);
        ov[1] = (bf16)((v1.y - mu) * r * sv.y + bv.y);
        ov[2] = (bf16)((v1.z - mu) * r * sv.z + bv.z);
        ov[3] = (bf16)((v1.w - mu) * r * sv.w + bv.w);
        *(bf16x4*)&ho[256 + lane * 4] = ov;
    }
}

// ---------------- GELU (tanh approximation, matches jax.nn.gelu) -------------------
__device__ inline float gelu_f(float x) {
    float u = 0.7978845608028654f * (x + 0.044715f * x * x * x);
    float t = 1.f - 2.f / (__expf(2.f * u) + 1.f);
    return 0.5f * x * (1.f + t);
}

// ---------------- GEMM: C[M,N] = A[M,K] @ Bt[N,K]^T (+epilogue) --------------------
// EPI 0: store bf16 | 1: +bias, gelu, store bf16 | 2: resid += | 3: resid += val+bias
// EPI 4: outf[perm(row)] = resid + val + bias (fp32, fused reorder_out)
// 128x128 tile, BK=32, 4 waves (2x2), global_load_lds staging, XOR kseg swizzle.
// Grid: (n_blocks, m_blocks). Epilogue via per-wave LDS transpose -> 16B stores.
template <int EPI>
__global__ __launch_bounds__(256) void k_gemm(const bf16* __restrict__ A,
                                              const bf16* __restrict__ Bt,
                                              const float* __restrict__ bias,
                                              float* __restrict__ resid,
                                              bf16* __restrict__ Cout,
                                              float* __restrict__ outf,
                                              int N, int K) {
    __shared__ __align__(16) char lds[17408];
    bf16* As = (bf16*)lds;                 // 128x32 bf16 = 8192 B, swizzled ksegs
    bf16* Bs = (bf16*)(lds + 8192);        // 128x32 bf16 = 8192 B
    int tid = threadIdx.x;
    int n0 = blockIdx.x * 128;
    int m0 = blockIdx.y * 128;
    int wave = tid >> 6, lane = tid & 63;
    int wm = (wave >> 1) * 64, wn = (wave & 1) * 64;
    int col = lane & 15, quad = lane >> 4;

    f32x4 acc[4][4] = {};

    int r0 = 2 * wave * 16 + (lane >> 2);
    int ksl = (lane & 3) ^ ((r0 >> 1) & 3);
    const bf16* ga0 = A + (size_t)(m0 + r0) * K + ksl * 8;
    const bf16* gb0 = Bt + (size_t)(n0 + r0) * K + ksl * 8;
    size_t rowK16 = (size_t)16 * K;
    bf16* la0 = &As[2 * wave * 512];
    bf16* la1 = &As[(2 * wave + 1) * 512];
    bf16* lb0 = &Bs[2 * wave * 512];
    bf16* lb1 = &Bs[(2 * wave + 1) * 512];

    for (int kb = 0; kb < K; kb += 32) {
        __syncthreads();
        async_ld16(ga0 + kb, la0);
        async_ld16(ga0 + rowK16 + kb, la1);
        async_ld16(gb0 + kb, lb0);
        async_ld16(gb0 + rowK16 + kb, lb1);
        __syncthreads();

        bf16x8 af[4], bfv[4];
#pragma unroll
        for (int i = 0; i < 4; i++) {
            int ra = wm + i * 16 + col;
            af[i] = *(const bf16x8*)&As[ra * 32 + ((quad ^ ((ra >> 1) & 3)) << 3)];
            int rb = wn + i * 16 + col;
            bfv[i] = *(const bf16x8*)&Bs[rb * 32 + ((quad ^ ((rb >> 1) & 3)) << 3)];
        }
#pragma unroll
        for (int mi = 0; mi < 4; mi++)
#pragma unroll
            for (int ni = 0; ni < 4; ni++)
                acc[mi][ni] = __builtin_amdgcn_mfma_f32_16x16x32_bf16(
                    af[mi], bfv[ni], acc[mi][ni], 0, 0, 0);
    }

    __syncthreads();   // LDS becomes epilogue scratch
    float* scrw = (float*)lds + wave * (16 * 68);

    int prow = lane >> 3;
    int pc0 = (lane & 7) * 8;
#pragma unroll
    for (int mi = 0; mi < 4; mi++) {
#pragma unroll
        for (int ni = 0; ni < 4; ni++)
#pragma unroll
            for (int r = 0; r < 4; r++)
                scrw[(quad * 4 + r) * 68 + ni * 16 + col] = acc[mi][ni][r];
#pragma unroll
        for (int h = 0; h < 2; h++) {
            int lr = h * 8 + prow;
            const float* sp = scrw + lr * 68 + pc0;
            float4 u0 = *(const float4*)sp;
            float4 u1 = *(const float4*)(sp + 4);
            int gm = m0 + wm + mi * 16 + lr;
            int gn = n0 + wn + pc0;
            size_t off = (size_t)gm * N + gn;
            if (EPI == 0) {
                bf16x8 ov;
                ov[0] = (bf16)u0.x; ov[1] = (bf16)u0.y; ov[2] = (bf16)u0.z; ov[3] = (bf16)u0.w;
                ov[4] = (bf16)u1.x; ov[5] = (bf16)u1.y; ov[6] = (bf16)u1.z; ov[7] = (bf16)u1.w;
                *(bf16x8*)&Cout[off] = ov;
            } else if (EPI == 1) {
                float4 b0 = *(const float4*)&bias[gn];
                float4 b1 = *(const float4*)&bias[gn + 4];
                bf16x8 ov;
                ov[0] = (bf16)gelu_f(u0.x + b0.x); ov[1] = (bf16)gelu_f(u0.y + b0.y);
                ov[2] = (bf16)gelu_f(u0.z + b0.z); ov[3] = (bf16)gelu_f(u0.w + b0.w);
                ov[4] = (bf16)gelu_f(u1.x + b1.x); ov[5] = (bf16)gelu_f(u1.y + b1.y);
                ov[6] = (bf16)gelu_f(u1.z + b1.z); ov[7] = (bf16)gelu_f(u1.w + b1.w);
                *(bf16x8*)&Cout[off] = ov;
            } else if (EPI == 2) {
                float4 r0v = *(const float4*)&resid[off];
                float4 r1v = *(const float4*)&resid[off + 4];
                r0v.x += u0.x; r0v.y += u0.y; r0v.z += u0.z; r0v.w += u0.w;
                r1v.x += u1.x; r1v.y += u1.y; r1v.z += u1.z; r1v.w += u1.w;
                *(float4*)&resid[off] = r0v;
                *(float4*)&resid[off + 4] = r1v;
            } else if (EPI == 3) {
                float4 b0 = *(const float4*)&bias[gn];
                float4 b1 = *(const float4*)&bias[gn + 4];
                float4 r0v = *(const float4*)&resid[off];
                float4 r1v = *(const float4*)&resid[off + 4];
                r0v.x += u0.x + b0.x; r0v.y += u0.y + b0.y;
                r0v.z += u0.z + b0.z; r0v.w += u0.w + b0.w;
                r1v.x += u1.x + b1.x; r1v.y += u1.y + b1.y;
                r1v.z += u1.z + b1.z; r1v.w += u1.w + b1.w;
                *(float4*)&resid[off] = r0v;
                *(float4*)&resid[off + 4] = r1v;
            } else {
                // EPI 4: fp32 out at permuted raw row (fused reorder_out)
                float4 b0 = *(const float4*)&bias[gn];
                float4 b1 = *(const float4*)&bias[gn + 4];
                float4 r0v = *(const float4*)&resid[off];
                float4 r1v = *(const float4*)&resid[off + 4];
                r0v.x += u0.x + b0.x; r0v.y += u0.y + b0.y;
                r0v.z += u0.z + b0.z; r0v.w += u0.w + b0.w;
                r1v.x += u1.x + b1.x; r1v.y += u1.y + b1.y;
                r1v.z += u1.z + b1.z; r1v.w += u1.w + b1.w;
                int wdx = gm / 49, n = gm - wdx * 49;
                int bb = wdx >> 6, r64 = wdx & 63;
                int n7 = n / 7;
                int yy = (r64 >> 3) * 7 + n7;
                int xx = (r64 & 7) * 7 + (n - n7 * 7);
                size_t traw = ((size_t)((bb * 56 + yy) * 56 + xx)) * 384 + gn;
                *(float4*)&outf[traw] = r0v;
                *(float4*)&outf[traw + 4] = r1v;
            }
        }
    }
}

// ---------------- MFMA window attention: one WAVE per (window, head) ---------------
__global__ __launch_bounds__(256) void k_attn(const bf16* __restrict__ qkv,
                                              const float* __restrict__ rpb,
                                              bf16* __restrict__ o) {
    __shared__ unsigned short relIdx[2401];
    __shared__ float rpbs[4][169];
    __shared__ __align__(16) bf16 Vs[4][32 * 72];
    __shared__ __align__(16) bf16 Ps[4][64 * 72];

    int tid = threadIdx.x;
    int wave = tid >> 6, lane = tid & 63;
    int col = lane & 15, quad = lane >> 4;
    int w = blockIdx.x;
    int head = blockIdx.y * 4 + wave;
    const float scale = 0.17677669529663687f;

    for (int e = tid; e < 2401; e += 256) {
        int i = e / 49, j = e - i * 49;
        int yi = i / 7, xi = i - yi * 7, yj = j / 7, xj = j - yj * 7;
        relIdx[e] = (unsigned short)((yi - yj + 6) * 13 + (xi - xj + 6));
    }
    for (int e = lane; e < 169; e += 64) rpbs[wave][e] = rpb[e * 12 + head];

    const bf16* base = qkv + (size_t)w * 49 * 1152 + head * 32;
    bf16* vsw = Vs[wave];
    bf16* psw = Ps[wave];

    bf16x4 z4 = {(bf16)0.f, (bf16)0.f, (bf16)0.f, (bf16)0.f};
    for (int e = lane; e < 576; e += 64) *(bf16x4*)&vsw[e * 4] = z4;
    for (int e = lane; e < 392; e += 64) {
        int j = e >> 3, d4 = (e & 7) * 4;
        bf16x4 vv = *(const bf16x4*)&base[768 + (size_t)j * 1152 + d4];
        vsw[(d4 + 0) * 72 + j] = vv[0];
        vsw[(d4 + 1) * 72 + j] = vv[1];
        vsw[(d4 + 2) * 72 + j] = vv[2];
        vsw[(d4 + 3) * 72 + j] = vv[3];
    }

    __syncthreads();

    bf16x8 qf[4], kf[4];
#pragma unroll
    for (int mi = 0; mi < 4; mi++) {
        size_t row = (size_t)(mi * 16 + col) * 1152 + quad * 8;
        qf[mi] = *(const bf16x8*)&base[row];
        kf[mi] = *(const bf16x8*)&base[384 + row];
    }

    f32x4 S[4][4] = {};
#pragma unroll
    for (int mi = 0; mi < 4; mi++)
#pragma unroll
        for (int nj = 0; nj < 4; nj++)
            S[mi][nj] = __builtin_amdgcn_mfma_f32_16x16x32_bf16(qf[mi], kf[nj], S[mi][nj], 0, 0, 0);

    float* rp = rpbs[wave];
#pragma unroll
    for (int mi = 0; mi < 4; mi++) {
#pragma unroll
        for (int r = 0; r < 4; r++) {
            int ii = mi * 16 + quad * 4 + r;
            int ir = (ii < 49 ? ii : 0) * 49;
            float sv[4];
            float mx = -1e30f;
#pragma unroll
            for (int nj = 0; nj < 4; nj++) {
                int j = nj * 16 + col;
                float v;
                if (j < 49) v = S[mi][nj][r] * scale + rp[relIdx[ir + j]];
                else v = -1e30f;
                sv[nj] = v;
                mx = fmaxf(mx, v);
            }
#pragma unroll
            for (int m = 1; m < 16; m <<= 1) mx = fmaxf(mx, __shfl_xor(mx, m));
            float sum = 0.f;
#pragma unroll
            for (int nj = 0; nj < 4; nj++) {
                float p = __expf(sv[nj] - mx);
                sv[nj] = p;
                sum += p;
            }
#pragma unroll
            for (int m = 1; m < 16; m <<= 1) sum += __shfl_xor(sum, m);
            float is = 1.f / sum;
#pragma unroll
            for (int nj = 0; nj < 4; nj++)
                psw[ii * 72 + nj * 16 + col] = (bf16)(sv[nj] * is);
        }
    }

    __syncthreads();

    f32x4 O[4][2] = {};
#pragma unroll
    for (int kt = 0; kt < 2; kt++) {
        bf16x8 vb[2];
#pragma unroll
        for (int nt = 0; nt < 2; nt++)
            vb[nt] = *(const bf16x8*)&vsw[(nt * 16 + col) * 72 + kt * 32 + quad * 8];
#pragma unroll
        for (int mi = 0; mi < 4; mi++) {
            bf16x8 pa = *(const bf16x8*)&psw[(mi * 16 + col) * 72 + kt * 32 + quad * 8];
#pragma unroll
            for (int nt = 0; nt < 2; nt++)
                O[mi][nt] = __builtin_amdgcn_mfma_f32_16x16x32_bf16(pa, vb[nt], O[mi][nt], 0, 0, 0);
        }
    }

    bf16* ob = o + (size_t)w * 49 * 384 + head * 32;
#pragma unroll
    for (int mi = 0; mi < 4; mi++) {
#pragma unroll
        for (int r = 0; r < 4; r++) {
            int i = mi * 16 + quad * 4 + r;
            if (i < 49) {
#pragma unroll
                for (int nt = 0; nt < 2; nt++)
                    ob[(size_t)i * 384 + nt * 16 + col] = (bf16)O[mi][nt][r];
            }
        }
    }
}

// ---------------- launch ----------------
extern "C" void kernel_launch(void* const* d_in, const int* in_sizes, int n_in,
                              void* d_out, int out_size, void* d_ws, size_t ws_size,
                              hipStream_t stream) {
    const float* x      = (const float*)d_in[0];
    const float* ln1_s  = (const float*)d_in[1];
    const float* ln1_b  = (const float*)d_in[2];
    const float* qkv_w  = (const float*)d_in[3];
    const float* rpb    = (const float*)d_in[4];
    const float* proj_w = (const float*)d_in[5];
    const float* ln2_s  = (const float*)d_in[6];
    const float* ln2_b  = (const float*)d_in[7];
    const float* mlp_w1 = (const float*)d_in[8];
    const float* mlp_b1 = (const float*)d_in[9];
    const float* mlp_w2 = (const float*)d_in[10];
    const float* mlp_b2 = (const float*)d_in[11];
    float* out = (float*)d_out;

    char* ws = (char*)d_ws;
    float* xres  = (float*)ws;                     // 77,070,336 B
    bf16* qkvbuf = (bf16*)(ws + 77070336);         // 115,605,504 B
    bf16* obuf   = (bf16*)(ws + 192675840);        // 38,535,168 B
    bf16* wbuf   = (bf16*)(ws + 231211008);        // 7,077,888 B
    bf16* hidden = qkvbuf;                         // aliases qkv+obuf (154,140,672 B)
    bf16* hbuf   = (bf16*)d_out;                   // 38.5 MB scratch inside 77 MB out

    bf16* qkvw_b  = wbuf;                 // 884,736 elems (2 layers, transposed [N][K])
    bf16* projw_b = wbuf + 884736;        // 294,912
    bf16* mlp1_b  = wbuf + 1179648;       // 1,179,648
    bf16* mlp2_b  = wbuf + 2359296;       // 1,179,648

    for (int l = 0; l < 2; l++) {
        k_f2bt<<<1728, 256, 0, stream>>>(qkv_w + (size_t)l * 442368,
                                         qkvw_b + (size_t)l * 442368, 384, 1152);
        k_f2bt<<<576, 256, 0, stream>>>(proj_w + (size_t)l * 147456,
                                        projw_b + (size_t)l * 147456, 384, 384);
        k_f2bt<<<2304, 256, 0, stream>>>(mlp_w1 + (size_t)l * 589824,
                                         mlp1_b + (size_t)l * 589824, 384, 1536);
        k_f2bt<<<2304, 256, 0, stream>>>(mlp_w2 + (size_t)l * 589824,
                                         mlp2_b + (size_t)l * 589824, 1536, 384);
    }

    // fused reorder_in + LN1(l=0)
    k_lnr<<<12544, 256, 0, stream>>>(x, ln1_s, ln1_b, xres, hbuf);

    for (int l = 0; l < 2; l++) {
        k_gemm<0><<<dim3(9, 392), 256, 0, stream>>>(
            hbuf, qkvw_b + (size_t)l * 442368, nullptr, nullptr, qkvbuf, nullptr, 1152, 384);
        k_attn<<<dim3(1024, 3), 256, 0, stream>>>(qkvbuf, rpb + l * 2028, obuf);
        k_gemm<2><<<dim3(3, 392), 256, 0, stream>>>(
            obuf, projw_b + (size_t)l * 147456, nullptr, xres, nullptr, nullptr, 384, 384);
        k_ln<<<12544, 256, 0, stream>>>(xres, ln2_s + l * 384, ln2_b + l * 384, hbuf);
        k_gemm<1><<<dim3(12, 392), 256, 0, stream>>>(
            hbuf, mlp1_b + (size_t)l * 589824, mlp_b1 + l * 1536, nullptr, hidden, nullptr, 1536, 384);
        if (l == 0) {
            k_gemm<3><<<dim3(3, 392), 256, 0, stream>>>(
                hidden, mlp2_b, mlp_b2, xres, nullptr, nullptr, 384, 1536);
            k_ln<<<12544, 256, 0, stream>>>(xres, ln1_s + 384, ln1_b + 384, hbuf);
        } else {
            k_gemm<4><<<dim3(3, 392), 256, 0, stream>>>(
                hidden, mlp2_b + 589824, mlp_b2 + 384, xres, nullptr, out, 384, 1536);
        }
    }
}